// Round 1
// baseline (403.902 us; speedup 1.0000x reference)
//
#include <hip/hip_runtime.h>

// FullNN: per-atom MLP (FEAT=64 -> tanh(HID=64) -> 1) + segment-sum over 32768 structures.
// 3 elements, 1M atoms each, all fp32. No fp32 MFMA on CDNA4 -> VALU kernel.
//
// Structure: 1 thread = 1 atom. x-row (64 f32) in VGPRs; W1/b1/W2/b2 accessed with
// wave-uniform indices through __restrict__ const pointers -> compiler emits scalar
// (s_load) reads through K$, so each MAC is a single v_fmac_f32 with an SGPR operand.

struct ElemPtrs {
    const float* x;
    const int*   idx;
    const float* W1;
    const float* b1;
    const float* W2;
    const float* b2;
};

struct Params {
    ElemPtrs e[3];
    int n_atoms;
};

__device__ __forceinline__ float fast_tanh(float v) {
    // tanh(v) = (e^{2v} - 1) / (e^{2v} + 1); clamp so exp2 stays finite.
    v = fminf(10.0f, fmaxf(-10.0f, v));
    float t = __builtin_amdgcn_exp2f(v * 2.8853900817779268f); // e^{2v} = 2^{2v*log2(e)}
    return (t - 1.0f) * __builtin_amdgcn_rcpf(t + 1.0f);
}

__global__ __launch_bounds__(256, 4) void atom_mlp_kernel(Params p, float* __restrict__ out) {
    const ElemPtrs ep = p.e[blockIdx.y];
    const int i = blockIdx.x * 256 + threadIdx.x;
    if (i >= p.n_atoms) return;

    // Load this atom's feature row (256 B) as 16 x float4 into registers.
    float xr[64];
    const float4* __restrict__ xv = reinterpret_cast<const float4*>(ep.x + (size_t)i * 64);
    #pragma unroll
    for (int c = 0; c < 16; ++c) {
        float4 v = xv[c];
        xr[4 * c + 0] = v.x;
        xr[4 * c + 1] = v.y;
        xr[4 * c + 2] = v.z;
        xr[4 * c + 3] = v.w;
    }

    const float* __restrict__ W1 = ep.W1;
    const float* __restrict__ b1 = ep.b1;
    const float* __restrict__ W2 = ep.W2;

    float atom_e = ep.b2[0];

    // 16 groups of 4 hidden units; inner k fully unrolled (256 fma per group).
    #pragma unroll 2
    for (int jg = 0; jg < 16; ++jg) {
        const int j0 = jg * 4;
        float a0 = b1[j0 + 0];
        float a1 = b1[j0 + 1];
        float a2 = b1[j0 + 2];
        float a3 = b1[j0 + 3];
        #pragma unroll
        for (int k = 0; k < 64; ++k) {
            const float xk = xr[k];
            a0 = fmaf(xk, W1[k * 64 + j0 + 0], a0);
            a1 = fmaf(xk, W1[k * 64 + j0 + 1], a1);
            a2 = fmaf(xk, W1[k * 64 + j0 + 2], a2);
            a3 = fmaf(xk, W1[k * 64 + j0 + 3], a3);
        }
        atom_e = fmaf(fast_tanh(a0), W2[j0 + 0], atom_e);
        atom_e = fmaf(fast_tanh(a1), W2[j0 + 1], atom_e);
        atom_e = fmaf(fast_tanh(a2), W2[j0 + 2], atom_e);
        atom_e = fmaf(fast_tanh(a3), W2[j0 + 3], atom_e);
    }

    atomicAdd(&out[ep.idx[i]], atom_e);
}

extern "C" void kernel_launch(void* const* d_in, const int* in_sizes, int n_in,
                              void* d_out, int out_size, void* d_ws, size_t ws_size,
                              hipStream_t stream) {
    Params p;
    for (int e = 0; e < 3; ++e) {
        p.e[e].x   = (const float*)d_in[6 * e + 0];
        p.e[e].idx = (const int*)  d_in[6 * e + 1];
        p.e[e].W1  = (const float*)d_in[6 * e + 2];
        p.e[e].b1  = (const float*)d_in[6 * e + 3];
        p.e[e].W2  = (const float*)d_in[6 * e + 4];
        p.e[e].b2  = (const float*)d_in[6 * e + 5];
    }
    p.n_atoms = in_sizes[0] / 64;

    float* out = (float*)d_out;
    // d_out is poisoned (0xAA) before timing and NOT re-zeroed between replays.
    hipMemsetAsync(out, 0, (size_t)out_size * sizeof(float), stream);

    dim3 grid((p.n_atoms + 255) / 256, 3);
    atom_mlp_kernel<<<grid, 256, 0, stream>>>(p, out);
}